// Round 12
// baseline (149.255 us; speedup 1.0000x reference)
//
#include <hip/hip_runtime.h>
#include <hip/hip_bf16.h>
#include <cstdint>

// Problem constants
#define NB   32      // batch
#define NC   256     // z channels
#define NE   128     // embed dim
#define NS   256     // H*W pixels per batch
#define NV   4096    // vocab
#define NP   8192    // total pixels
#define NSPLIT 8     // vocab splits (512 codes each)

typedef unsigned short ushort_t;
typedef __attribute__((ext_vector_type(8))) short bf16x8;
typedef __attribute__((ext_vector_type(8))) unsigned short us8;
typedef __attribute__((ext_vector_type(4))) float f32x4;

__device__ __forceinline__ ushort_t f2bf(float f) {
    __hip_bfloat16 h = __float2bfloat16(f);
    ushort_t u; __builtin_memcpy(&u, &h, 2); return u;
}
__device__ __forceinline__ unsigned asu(float f) { unsigned u; __builtin_memcpy(&u,&f,4); return u; }
__device__ __forceinline__ float    asf(unsigned u) { float f; __builtin_memcpy(&f,&u,4); return f; }

// ---------------------------------------------------------------------------
// K0: pack emb hi-bf16 into Bpack (MFMA B-frag order) + cnorm. (Validated.)
// Bpack (ushort units): [(G*4 + ks)*512 + L*8 + j],
//   element = emb[code = G*16 + (L&15)][k = ks*32 + (L>>4)*8 + j]
// ---------------------------------------------------------------------------
__global__ __launch_bounds__(256) void pack_emb(
    const float* __restrict__ emb, ushort_t* __restrict__ Bpack,
    float* __restrict__ cnorm)
{
    const int t = threadIdx.x;
    const int v     = blockIdx.x * 32 + (t >> 3);
    const int chunk = t & 7;
    const float4* rp = (const float4*)(emb + (size_t)v * NE + chunk * 16);
    float4 x0 = rp[0], x1 = rp[1], x2 = rp[2], x3 = rp[3];
    float xs[16] = { x0.x, x0.y, x0.z, x0.w, x1.x, x1.y, x1.z, x1.w,
                     x2.x, x2.y, x2.z, x2.w, x3.x, x3.y, x3.z, x3.w };
    us8 h0, h1;
    float nn = 0.f;
#pragma unroll
    for (int j = 0; j < 8; j++) {
        nn = fmaf(xs[j], xs[j], nn);
        h0[j] = f2bf(xs[j]);
    }
#pragma unroll
    for (int j = 0; j < 8; j++) {
        nn = fmaf(xs[8 + j], xs[8 + j], nn);
        h1[j] = f2bf(xs[8 + j]);
    }
    nn += __shfl_xor(nn, 1);
    nn += __shfl_xor(nn, 2);
    nn += __shfl_xor(nn, 4);
    if (chunk == 0) cnorm[v] = 0.5f * nn;

    const int G  = v >> 4;
    const int ks = chunk >> 1;
    const int q0 = (chunk & 1) * 2;
    const int L0 = (v & 15) | (q0 << 4);
    const int L1 = (v & 15) | ((q0 + 1) << 4);
    *(us8*)(Bpack + ((size_t)G * 4 + ks) * 512 + L0 * 8) = h0;
    *(us8*)(Bpack + ((size_t)G * 4 + ks) * 512 + L1 * 8) = h1;
}

// ---------------------------------------------------------------------------
// vq_front: P1+P2+P3 of round-11's vq_main, BYTE-IDENTICAL bodies; the only
// change is the top-4 result is written to global pidx4 (round-0 layout
// [(split*NP + p)*4 + j]) instead of block-local LDS. Attribution round:
// this kernel's dispatch time = true cost of pre_conv + MFMA scoring.
// 256 blocks x 512 threads.
// ---------------------------------------------------------------------------
#define ZE_STR  36
#define ZL_STR  132
#define ZE_OFF  0            // 256*36*4 = 36864
#define R1_OFF  0            // 2*64*33*4 = 16896  (aliases ze, dead after P2)
#define R2_OFF  16896        // 16896
#define ZL_OFF  36864        // 32*132*4 = 16896
#define T4B_OFF 53760        // 2*32*4*4*4 = 4096
#define SM_SIZE 57856

__global__ __launch_bounds__(512, 2) void vq_front(
    const float* __restrict__ z_e, const float* __restrict__ pre_w,
    const float* __restrict__ pre_b,
    const ushort_t* __restrict__ Bpack, const float* __restrict__ cnorm,
    float* __restrict__ out_z, int* __restrict__ pidx4)
{
    __shared__ __align__(16) char smraw[SM_SIZE];
    float* ze   = (float*)(smraw + ZE_OFF);
    float* r1   = (float*)(smraw + R1_OFF);
    float* r2   = (float*)(smraw + R2_OFF);
    float* zl   = (float*)(smraw + ZL_OFF);
    float* t4b  = (float*)(smraw + T4B_OFF);

    const int t  = threadIdx.x;
    const int b  = blockIdx.x >> 3;
    const int s0 = (blockIdx.x & 7) * 32;

    // ================= P1: stage z_e[b, :, s0..s0+32] =================
    for (int idx = t; idx < NC * 32; idx += 512) {
        int c = idx >> 5, i = idx & 31;
        ze[c * ZE_STR + i] = z_e[((size_t)b * NC + c) * NS + s0 + i];
    }
    __syncthreads();

    // ================= P2: z-GEMM (f32) ===============================
    {
        const int pg = t >> 7;       // px group of 8
        const int e  = t & 127;      // embed row
        const float* wr = pre_w + (size_t)e * NC;
        float a0 = 0.f, a1 = 0.f, a2 = 0.f, a3 = 0.f;
        float a4 = 0.f, a5 = 0.f, a6 = 0.f, a7 = 0.f;
#pragma unroll 2
        for (int c = 0; c < NC; c += 4) {
            float4 w4 = *(const float4*)(wr + c);
            float4 za, zb;
            za = *(const float4*)&ze[(c + 0) * ZE_STR + pg * 8];
            zb = *(const float4*)&ze[(c + 0) * ZE_STR + pg * 8 + 4];
            a0 = fmaf(w4.x, za.x, a0); a1 = fmaf(w4.x, za.y, a1);
            a2 = fmaf(w4.x, za.z, a2); a3 = fmaf(w4.x, za.w, a3);
            a4 = fmaf(w4.x, zb.x, a4); a5 = fmaf(w4.x, zb.y, a5);
            a6 = fmaf(w4.x, zb.z, a6); a7 = fmaf(w4.x, zb.w, a7);
            za = *(const float4*)&ze[(c + 1) * ZE_STR + pg * 8];
            zb = *(const float4*)&ze[(c + 1) * ZE_STR + pg * 8 + 4];
            a0 = fmaf(w4.y, za.x, a0); a1 = fmaf(w4.y, za.y, a1);
            a2 = fmaf(w4.y, za.z, a2); a3 = fmaf(w4.y, za.w, a3);
            a4 = fmaf(w4.y, zb.x, a4); a5 = fmaf(w4.y, zb.y, a5);
            a6 = fmaf(w4.y, zb.z, a6); a7 = fmaf(w4.y, zb.w, a7);
            za = *(const float4*)&ze[(c + 2) * ZE_STR + pg * 8];
            zb = *(const float4*)&ze[(c + 2) * ZE_STR + pg * 8 + 4];
            a0 = fmaf(w4.z, za.x, a0); a1 = fmaf(w4.z, za.y, a1);
            a2 = fmaf(w4.z, za.z, a2); a3 = fmaf(w4.z, za.w, a3);
            a4 = fmaf(w4.z, zb.x, a4); a5 = fmaf(w4.z, zb.y, a5);
            a6 = fmaf(w4.z, zb.z, a6); a7 = fmaf(w4.z, zb.w, a7);
            za = *(const float4*)&ze[(c + 3) * ZE_STR + pg * 8];
            zb = *(const float4*)&ze[(c + 3) * ZE_STR + pg * 8 + 4];
            a0 = fmaf(w4.w, za.x, a0); a1 = fmaf(w4.w, za.y, a1);
            a2 = fmaf(w4.w, za.z, a2); a3 = fmaf(w4.w, za.w, a3);
            a4 = fmaf(w4.w, zb.x, a4); a5 = fmaf(w4.w, zb.y, a5);
            a6 = fmaf(w4.w, zb.z, a6); a7 = fmaf(w4.w, zb.w, a7);
        }
        const float bias = pre_b[e];
        a0 += bias; a1 += bias; a2 += bias; a3 += bias;
        a4 += bias; a5 += bias; a6 += bias; a7 += bias;
        zl[(pg * 8 + 0) * ZL_STR + e] = a0;
        zl[(pg * 8 + 1) * ZL_STR + e] = a1;
        zl[(pg * 8 + 2) * ZL_STR + e] = a2;
        zl[(pg * 8 + 3) * ZL_STR + e] = a3;
        zl[(pg * 8 + 4) * ZL_STR + e] = a4;
        zl[(pg * 8 + 5) * ZL_STR + e] = a5;
        zl[(pg * 8 + 6) * ZL_STR + e] = a6;
        zl[(pg * 8 + 7) * ZL_STR + e] = a7;
        float4 lo = { a0, a1, a2, a3 };
        float4 hi = { a4, a5, a6, a7 };
        float* dst = out_z + ((size_t)b * NE + e) * NS + s0 + pg * 8;
        *(float4*)(dst + 0) = lo;
        *(float4*)(dst + 4) = hi;
    }
    __syncthreads();

    // ================= P3: MFMA scoring + top-4/split =================
    const int wave = t >> 6, lane = t & 63;
    const int am = lane & 15, aq = lane >> 4;

    bf16x8 ah[2][4];
#pragma unroll
    for (int mt = 0; mt < 2; mt++)
#pragma unroll
        for (int ks = 0; ks < 4; ks++) {
            const unsigned* src = (const unsigned*)(zl + (mt * 16 + am) * ZL_STR + ks * 32 + aq * 8);
            union { unsigned u[4]; bf16x8 v; } pk;
#pragma unroll
            for (int pr = 0; pr < 4; pr++)
                pk.u[pr] = (src[2 * pr + 1] & 0xFFFF0000u) | (src[2 * pr] >> 16);
            ah[mt][ks] = pk.v;
        }

    const int wq = wave >> 2;      // split half within pair
    const int wv = wave & 3;       // plays validated kernel's "wave"

    for (int sp = 0; sp < NSPLIT; sp += 2) {
        const int split = sp + wq;
        const int Gbase = split * 32 + wv * 8;
        float cn[8];
#pragma unroll
        for (int cgi = 0; cgi < 8; cgi++)
            cn[cgi] = cnorm[(Gbase + cgi) * 16 + am];

        float b1v[8], b2v[8];
#pragma unroll
        for (int i = 0; i < 8; i++) { b1v[i] = -1e30f; b2v[i] = -1e30f; }

        bf16x8 bh[4], bhn[4];
#pragma unroll
        for (int ks = 0; ks < 4; ks++)
            bh[ks] = *(const bf16x8*)(Bpack + ((size_t)Gbase * 4 + ks) * 512 + lane * 8);

        for (int cgi = 0; cgi < 8; cgi++) {
            if (cgi < 7) {
#pragma unroll
                for (int ks = 0; ks < 4; ks++)
                    bhn[ks] = *(const bf16x8*)(Bpack + ((size_t)(Gbase + cgi + 1) * 4 + ks) * 512 + lane * 8);
            }
            f32x4 acc[2];
#pragma unroll
            for (int mt = 0; mt < 2; mt++) acc[mt] = (f32x4){0.f, 0.f, 0.f, 0.f};
#pragma unroll
            for (int ks = 0; ks < 4; ks++)
#pragma unroll
                for (int mt = 0; mt < 2; mt++)
                    acc[mt] = __builtin_amdgcn_mfma_f32_16x16x32_bf16(ah[mt][ks], bh[ks], acc[mt], 0, 0, 0);

#pragma unroll
            for (int mt = 0; mt < 2; mt++)
#pragma unroll
                for (int reg = 0; reg < 4; reg++) {
                    const int si = mt * 4 + reg;
                    float sc = acc[mt][reg] - cn[cgi];
                    float ev = asf((asu(sc) & ~7u) | (unsigned)cgi);
                    b2v[si] = fmaxf(b2v[si], fminf(ev, b1v[si]));
                    b1v[si] = fmaxf(b1v[si], ev);
                }
#pragma unroll
            for (int ks = 0; ks < 4; ks++) bh[ks] = bhn[ks];
        }

        const int slot = wv * 16 + am;
#pragma unroll
        for (int mt = 0; mt < 2; mt++)
#pragma unroll
            for (int reg = 0; reg < 4; reg++) {
                int px = mt * 16 + aq * 4 + reg;
                r1[(wq * 64 + slot) * 33 + px] = b1v[mt * 4 + reg];
                r2[(wq * 64 + slot) * 33 + px] = b2v[mt * 4 + reg];
            }
        __syncthreads();

        if (t < 256) {
            const int wq2 = t >> 7, rem = t & 127;
            const int px = rem >> 2, ch = rem & 3;
            float t1 = -1e30f, t2 = -1e30f, t3 = -1e30f, t4 = -1e30f;
            for (int i = 0; i < 16; i++) {
                int sl = ch * 16 + i;
#pragma unroll
                for (int e = 0; e < 2; e++) {
                    float raw = e ? r2[(wq2 * 64 + sl) * 33 + px]
                                  : r1[(wq2 * 64 + sl) * 33 + px];
                    unsigned vb = asu(raw);
                    float v = asf((vb & ~511u) | ((unsigned)sl << 3) | (vb & 7u));
                    t4 = fmaxf(t4, fminf(v, t3));
                    t3 = fmaxf(t3, fminf(v, t2));
                    t2 = fmaxf(t2, fminf(v, t1));
                    t1 = fmaxf(t1, v);
                }
            }
            float* dst = t4b + ((wq2 * 32 + px) * 4 + ch) * 4;
            dst[0] = t1; dst[1] = t2; dst[2] = t3; dst[3] = t4;
        }
        __syncthreads();

        if (t < 64) {
            const int wq2 = t >> 5, px = t & 31;
            float u1 = -1e30f, u2 = -1e30f, u3 = -1e30f, u4 = -1e30f;
            for (int ch = 0; ch < 4; ch++) {
#pragma unroll
                for (int j = 0; j < 4; j++) {
                    float v = t4b[((wq2 * 32 + px) * 4 + ch) * 4 + j];
                    u4 = fmaxf(u4, fminf(v, u3));
                    u3 = fmaxf(u3, fminf(v, u2));
                    u2 = fmaxf(u2, fminf(v, u1));
                    u1 = fmaxf(u1, v);
                }
            }
            const int spw = sp + wq2;
            const int p = blockIdx.x * 32 + px;      // global pixel
            float uu[4] = { u1, u2, u3, u4 };
#pragma unroll
            for (int j = 0; j < 4; j++) {
                unsigned bits = asu(uu[j]) & 511u;
                int w = (int)(bits >> 7), res = (int)((bits >> 3) & 15u), cg = (int)(bits & 7u);
                pidx4[((size_t)spw * NP + p) * 4 + j] = spw * 512 + (w * 8 + cg) * 16 + res;
            }
        }
        __syncthreads();
    }
}

// ---------------------------------------------------------------------------
// vq_back: VERBATIM round-4 rescore_gather_post2 (measured anchor: 46 µs).
// 512 blocks x 512 threads, 16 px/block. Exact f64 rescore (1 cand/thread,
// 4-way partials, 32-lane shfl argmax, tie -> lowest idx), gather, post_conv.
// ---------------------------------------------------------------------------
__global__ __launch_bounds__(512, 4) void vq_back(
    const float* __restrict__ z, const float* __restrict__ emb,
    const int* __restrict__ pidx4, const float* __restrict__ post_w,
    const float* __restrict__ post_b, float* __restrict__ out_zq,
    float* __restrict__ out_rec)
{
    __shared__ __align__(16) float zl[16 * 132];   // 8448 B
    __shared__ __align__(16) float eg[16 * 132];   // 8448 B
    __shared__ int tok[16];                        //   64 B

    const int t  = threadIdx.x;
    const int p0 = blockIdx.x * 16;
    const int b  = p0 >> 8;
    const int s0 = p0 & 255;

    // ---- stage z rows: [px][k], padded stride 132 ----
    for (int idx = t; idx < 16 * 128; idx += 512) {
        int k = idx >> 4, i = idx & 15;
        zl[i * 132 + k] = z[(size_t)(b * NE + k) * NS + s0 + i];
    }
    __syncthreads();

    // ---- exact f64 rescore: 32 threads/px, 1 candidate each ----
    {
        const int il = t >> 5;   // px local 0..15
        const int cc = t & 31;   // candidate 0..31
        const int p  = p0 + il;
        const int split = cc >> 2, slot = cc & 3;
        const int idx = pidx4[((size_t)split * NP + p) * 4 + slot];
        const float* er = emb + (size_t)idx * NE;
        const float* zr = &zl[il * 132];

        double d0 = 0.0, d1 = 0.0, d2 = 0.0, d3 = 0.0;
        double n0 = 0.0, n1 = 0.0, n2 = 0.0, n3 = 0.0;
#pragma unroll
        for (int k = 0; k < NE; k += 16) {
            float4 e0 = *(const float4*)(er + k + 0);
            float4 e1 = *(const float4*)(er + k + 4);
            float4 e2 = *(const float4*)(er + k + 8);
            float4 e3 = *(const float4*)(er + k + 12);
            float4 z0 = *(const float4*)(zr + k + 0);
            float4 z1 = *(const float4*)(zr + k + 4);
            float4 z2 = *(const float4*)(zr + k + 8);
            float4 z3 = *(const float4*)(zr + k + 12);
            d0 += (double)z0.x * e0.x; d0 += (double)z0.y * e0.y;
            d0 += (double)z0.z * e0.z; d0 += (double)z0.w * e0.w;
            d1 += (double)z1.x * e1.x; d1 += (double)z1.y * e1.y;
            d1 += (double)z1.z * e1.z; d1 += (double)z1.w * e1.w;
            d2 += (double)z2.x * e2.x; d2 += (double)z2.y * e2.y;
            d2 += (double)z2.z * e2.z; d2 += (double)z2.w * e2.w;
            d3 += (double)z3.x * e3.x; d3 += (double)z3.y * e3.y;
            d3 += (double)z3.z * e3.z; d3 += (double)z3.w * e3.w;
            n0 += (double)e0.x * e0.x; n0 += (double)e0.y * e0.y;
            n0 += (double)e0.z * e0.z; n0 += (double)e0.w * e0.w;
            n1 += (double)e1.x * e1.x; n1 += (double)e1.y * e1.y;
            n1 += (double)e1.z * e1.z; n1 += (double)e1.w * e1.w;
            n2 += (double)e2.x * e2.x; n2 += (double)e2.y * e2.y;
            n2 += (double)e2.z * e2.z; n2 += (double)e2.w * e2.w;
            n3 += (double)e3.x * e3.x; n3 += (double)e3.y * e3.y;
            n3 += (double)e3.z * e3.z; n3 += (double)e3.w * e3.w;
        }
        double bs = ((d0 + d1) + (d2 + d3)) - 0.5 * ((n0 + n1) + (n2 + n3));
        int bi = idx;
#pragma unroll
        for (int m = 1; m <= 16; m <<= 1) {
            double osc = __shfl_xor(bs, m);
            int    obi = __shfl_xor(bi, m);
            if (osc > bs || (osc == bs && obi < bi)) { bs = osc; bi = obi; }
        }
        if (cc == 0) tok[il] = bi;
    }
    __syncthreads();

    // ---- gather: write out_zq and stage eg[px][k] ----
    for (int idx = t; idx < NE * 16; idx += 512) {
        int e = idx >> 4, i = idx & 15;
        float v = emb[(size_t)tok[i] * NE + e];
        out_zq[(size_t)(b * NE + e) * NS + s0 + i] = v;
        eg[i * 132 + e] = v;
    }
    __syncthreads();

    // ---- post_conv: thread = (c, ph); 8 px each; w row from L2 ----
    {
        const int c  = t & 255;
        const int ph = t >> 8;          // pixel half
        const int pb = ph * 8;
        const float* wr = post_w + (size_t)c * NE;

        float a0 = 0.f, a1 = 0.f, a2 = 0.f, a3 = 0.f;
        float a4 = 0.f, a5 = 0.f, a6 = 0.f, a7 = 0.f;
#pragma unroll 4
        for (int k = 0; k < NE; k += 4) {
            float4 w4 = *(const float4*)(wr + k);
            float4 q;
            q = *(const float4*)&eg[(pb + 0) * 132 + k];
            a0 = fmaf(w4.x, q.x, fmaf(w4.y, q.y, fmaf(w4.z, q.z, fmaf(w4.w, q.w, a0))));
            q = *(const float4*)&eg[(pb + 1) * 132 + k];
            a1 = fmaf(w4.x, q.x, fmaf(w4.y, q.y, fmaf(w4.z, q.z, fmaf(w4.w, q.w, a1))));
            q = *(const float4*)&eg[(pb + 2) * 132 + k];
            a2 = fmaf(w4.x, q.x, fmaf(w4.y, q.y, fmaf(w4.z, q.z, fmaf(w4.w, q.w, a2))));
            q = *(const float4*)&eg[(pb + 3) * 132 + k];
            a3 = fmaf(w4.x, q.x, fmaf(w4.y, q.y, fmaf(w4.z, q.z, fmaf(w4.w, q.w, a3))));
            q = *(const float4*)&eg[(pb + 4) * 132 + k];
            a4 = fmaf(w4.x, q.x, fmaf(w4.y, q.y, fmaf(w4.z, q.z, fmaf(w4.w, q.w, a4))));
            q = *(const float4*)&eg[(pb + 5) * 132 + k];
            a5 = fmaf(w4.x, q.x, fmaf(w4.y, q.y, fmaf(w4.z, q.z, fmaf(w4.w, q.w, a5))));
            q = *(const float4*)&eg[(pb + 6) * 132 + k];
            a6 = fmaf(w4.x, q.x, fmaf(w4.y, q.y, fmaf(w4.z, q.z, fmaf(w4.w, q.w, a6))));
            q = *(const float4*)&eg[(pb + 7) * 132 + k];
            a7 = fmaf(w4.x, q.x, fmaf(w4.y, q.y, fmaf(w4.z, q.z, fmaf(w4.w, q.w, a7))));
        }
        const float bias = post_b[c];
        float4 lo = { a0 + bias, a1 + bias, a2 + bias, a3 + bias };
        float4 hi = { a4 + bias, a5 + bias, a6 + bias, a7 + bias };
        float* dst = out_rec + (size_t)(b * NC + c) * NS + s0 + pb;
        *(float4*)(dst + 0) = lo;
        *(float4*)(dst + 4) = hi;
    }
}

// ---------------------------------------------------------------------------
extern "C" void kernel_launch(void* const* d_in, const int* in_sizes, int n_in,
                              void* d_out, int out_size, void* d_ws, size_t ws_size,
                              hipStream_t stream)
{
    const float* z_e    = (const float*)d_in[0];
    const float* pre_w  = (const float*)d_in[1];
    const float* pre_b  = (const float*)d_in[2];
    const float* emb    = (const float*)d_in[3];
    const float* post_w = (const float*)d_in[4];
    const float* post_b = (const float*)d_in[5];

    // d_out: fp32 x 4194304 = (z 1048576 | z_q 1048576 | rec 2097152)
    float* out     = (float*)d_out;
    float* out_z   = out;
    float* out_zq  = out + 1048576;
    float* out_rec = out + 2097152;

    // Scratch: Bpack 1 MB + cnorm 16 KB + pidx4 1 MB (round-0 footprint;
    // d_ws path has always been taken in this harness).
    const size_t SZ_BPACK = (size_t)256 * 4 * 512 * 2;            // 1 MB
    const size_t SZ_CNORM = (size_t)NV * 4;                       // 16 KB
    const size_t SZ_PIDX4 = (size_t)NSPLIT * NP * 4 * 4;          // 1 MB
    const size_t NEED = SZ_BPACK + SZ_CNORM + SZ_PIDX4;
    char* scr = (ws_size >= NEED) ? (char*)d_ws : (char*)out_rec;
    ushort_t* Bpack = (ushort_t*)scr;
    float*    cnorm = (float*)(scr + SZ_BPACK);
    int*      pidx4 = (int*)(scr + SZ_BPACK + SZ_CNORM);

    pack_emb<<<dim3(128), 256, 0, stream>>>(emb, Bpack, cnorm);
    vq_front<<<dim3(256), 512, 0, stream>>>(z_e, pre_w, pre_b, Bpack, cnorm,
                                            out_z, pidx4);
    vq_back <<<dim3(512), 512, 0, stream>>>(out_z, emb, pidx4,
                                            post_w, post_b, out_zq, out_rec);
}